// Round 5
// baseline (7122.652 us; speedup 1.0000x reference)
//
#include <hip/hip_runtime.h>
#include <stdint.h>

// Problem constants (DecoderLSTM): VOCAB=50257, E=H=512, B=32, S=512
// ALL float tensors are fp32; sequence is int32. Internal bf16 MFMA; fp32 out.
#define EDIM  512
#define HDIM  512
#define BSZ   32
#define SLEN  512
#define GDIM  2048   // 4*H
#define GWG   32     // number of scan workgroups (h-column split)

#define SENT 0x7F7F7F7F7F7F7F7FULL   // 4x bf16 0x7F7F = 3.39e38, unreachable for |h|<1

typedef __bf16 bf16x8 __attribute__((ext_vector_type(8)));
typedef float  f32x4  __attribute__((ext_vector_type(4)));

__device__ __forceinline__ uint16_t f2bf(float f) {
  union { float f; uint32_t i; } v; v.f = f;
  uint32_t r = v.i + 0x7FFFu + ((v.i >> 16) & 1u);  // RNE
  return (uint16_t)(r >> 16);
}
__device__ __forceinline__ float bf2f(uint32_t u) {
  union { uint32_t i; float f; } v; v.i = u << 16; return v.f;
}
union BF8 { uint16_t u[8]; uint4 v; bf16x8 b; unsigned long long q[2]; };
union BF4 { uint16_t u[4]; unsigned long long q; };
__device__ __forceinline__ uint4 pack8(float4 lo, float4 hi) {
  BF8 r;
  r.u[0] = f2bf(lo.x); r.u[1] = f2bf(lo.y); r.u[2] = f2bf(lo.z); r.u[3] = f2bf(lo.w);
  r.u[4] = f2bf(hi.x); r.u[5] = f2bf(hi.y); r.u[6] = f2bf(hi.z); r.u[7] = f2bf(hi.w);
  return r.v;
}
__device__ __forceinline__ float sigm(float x) { return 1.0f / (1.0f + __expf(-x)); }
__device__ __forceinline__ float tanh_(float x) {
  float ax = fabsf(x);
  float e  = __expf(2.0f * ax);          // overflow-safe: e=inf -> t=1
  float t  = 1.0f - 2.0f / (e + 1.0f);
  return copysignf(t, x);
}
__device__ __forceinline__ unsigned long long allc(const unsigned long long* p) {
  return __hip_atomic_load(p, __ATOMIC_RELAXED, __HIP_MEMORY_SCOPE_AGENT);
}

// ---------------------------------------------------------------------------
// K1: const[g][b] = sum_k W_hh[g][k]*h0[b][k] + b_ih[g] + b_hh[g] (fp32)
// ---------------------------------------------------------------------------
__global__ __launch_bounds__(256) void k_const(
    const float* __restrict__ Whh, const float* __restrict__ h0,
    const float* __restrict__ bih, const float* __restrict__ bhh,
    float* __restrict__ cgb)
{
  int idx = blockIdx.x * 256 + threadIdx.x;        // 2048*32 = 65536
  int g = idx >> 5, b = idx & 31;
  const float4* w4 = (const float4*)(Whh + (size_t)g * HDIM);
  const float4* h4 = (const float4*)(h0  + (size_t)b * HDIM);
  float acc = 0.f;
  #pragma unroll 8
  for (int k = 0; k < HDIM / 4; k++) {
    float4 a = w4[k], c = h4[k];
    acc += a.x * c.x + a.y * c.y + a.z * c.z + a.w * c.w;
  }
  acc += bih[g] + bhh[g];
  cgb[idx] = acc;   // layout [g][b]
}

// ---------------------------------------------------------------------------
// K2: eg[s][b][g] (bf16) = sum_e emb[seq[b][s]][e] * W_ih[g][e] + const[g][b]
// Per WG: 64 gate rows (bf16, frag-order, 64KB LDS) x 4 s values.
// MFMA 16x16x32_bf16: A = W_e chunk (M=g), B = gathered emb rows (N=b).
// ---------------------------------------------------------------------------
__global__ __launch_bounds__(256) void k_emb(
    const int* __restrict__ seq, const float* __restrict__ emb,
    const float* __restrict__ Wih, const float* __restrict__ cgb,
    uint16_t* __restrict__ eg)
{
  __shared__ uint4 wlds[4096];   // 64KB bf16, frag-order: [T=n>>4][kc][nl=n&15][q]
  const int tid = threadIdx.x;
  const int gc  = blockIdx.x & 31;   // 32 g-chunks of 64 rows
  const int sc  = blockIdx.x >> 5;   // 128 s-chunks of 4
  const int g0  = gc * 64, s0 = sc * 4;

  for (int i = tid; i < 64 * 64; i += 256) {       // 64 rows x 64 8-elem chunks
    int n = i >> 6, c = i & 63;
    const float* wp = Wih + (size_t)(g0 + n) * 1024 + c * 8;   // W_e = W_ih[:, :512]
    float4 lo = *(const float4*)(wp);
    float4 hi = *(const float4*)(wp + 4);
    wlds[(((n >> 4) * 16 + (c >> 2)) << 6) + ((n & 15) << 2) + (c & 3)] = pack8(lo, hi);
  }
  __syncthreads();

  const int lane = tid & 63, w = tid >> 6;
  const int q = lane >> 4, nl = lane & 15;
  const int Nt  = w & 1;            // b-tile
  const int Mt0 = (w >> 1) * 2;     // g-tile pair {Mt0, Mt0+1}
  const int bcol = Nt * 16 + nl;

  float c0i[4], c1i[4];             // baked const, fixed across s
  #pragma unroll
  for (int r = 0; r < 4; r++) {
    c0i[r] = cgb[(g0 + (Mt0    ) * 16 + q * 4 + r) * 32 + bcol];
    c1i[r] = cgb[(g0 + (Mt0 + 1) * 16 + q * 4 + r) * 32 + bcol];
  }

  for (int si = 0; si < 4; si++) {
    int s = s0 + si;
    int rowi = seq[bcol * SLEN + s];                 // gather index for this lane's b
    const float* brow = emb + (size_t)rowi * EDIM + q * 8;
    f32x4 acc0, acc1;
    #pragma unroll
    for (int r = 0; r < 4; r++) { acc0[r] = c0i[r]; acc1[r] = c1i[r]; }
    #pragma unroll 4
    for (int kc = 0; kc < 16; kc++) {
      float4 blo = *(const float4*)(brow + kc * 32);
      float4 bhi = *(const float4*)(brow + kc * 32 + 4);
      BF8 bf; bf.v = pack8(blo, bhi);
      BF8 a0; a0.v = wlds[(((Mt0    ) * 16 + kc) << 6) + (nl << 2) + q];
      BF8 a1; a1.v = wlds[(((Mt0 + 1) * 16 + kc) << 6) + (nl << 2) + q];
      acc0 = __builtin_amdgcn_mfma_f32_16x16x32_bf16(a0.b, bf.b, acc0, 0, 0, 0);
      acc1 = __builtin_amdgcn_mfma_f32_16x16x32_bf16(a1.b, bf.b, acc1, 0, 0, 0);
    }
    #pragma unroll
    for (int r = 0; r < 4; r++) {
      int m0 = (Mt0    ) * 16 + q * 4 + r;
      int m1 = (Mt0 + 1) * 16 + q * 4 + r;
      eg[((size_t)s * 32 + bcol) * GDIM + g0 + m0] = f2bf(acc0[r]);   // [s][b][g]
      eg[((size_t)s * 32 + bcol) * GDIM + g0 + m1] = f2bf(acc1[r]);
    }
  }
}

// ---------------------------------------------------------------------------
// K3: sequential scan, barrier-free, 512-slot h history with sentinel polling.
// R5 change vs R4: straggler respin is now PARALLEL ROUNDS — reload all 32
// u64s (independent, one latency per round; a valid u64 reloads to the same
// value since each slot u64 is written exactly once) and re-check, instead of
// 32 serial dependent re-polls (R4's 8 µs/step bug). h store issues BEFORE
// the cached out store (h visibility is the inter-WG critical path).
// ---------------------------------------------------------------------------
__global__ __launch_bounds__(128) void k_scan(
    const float* __restrict__ Wih, const float* __restrict__ c0,
    const uint16_t* __restrict__ eg, unsigned long long* __restrict__ hbuf,
    float* __restrict__ out)
{
  __shared__ uint4 wlds[4096];   // 64KB
  const int tid = threadIdx.x;
  const int wg  = blockIdx.x;
  const int j0  = wg * 16;

  // Stage W_h slice: row n: gate=n>>4, jj=n&15 -> W_ih row gate*512+j0+jj, cols [512,1024)
  for (int i = tid; i < 64 * 64; i += 128) {
    int n = i >> 6, c = i & 63;
    int grow = (n >> 4) * HDIM + j0 + (n & 15);
    const float* wp = Wih + (size_t)grow * 1024 + 512 + c * 8;
    float4 lo = *(const float4*)(wp);
    float4 hi = *(const float4*)(wp + 4);
    wlds[(((n >> 4) * 16 + (c >> 2)) << 6) + ((n & 15) << 2) + (c & 3)] = pack8(lo, hi);
  }

  const int lane = tid & 63, w = tid >> 6;   // w = batch half (N-tile)
  const int q = lane >> 4, nl = lane & 15;
  const int b  = w * 16 + nl;                // owned batch (C col)
  const int jq = j0 + q * 4;                 // owned j's: jq..jq+3 (C rows)
  float c0r[4];
  #pragma unroll
  for (int r = 0; r < 4; r++) c0r[r] = c0[(size_t)b * HDIM + jq + r];
  __syncthreads();   // LDS W_h ready (only barrier in the kernel)

  for (int t = 0; t < SLEN; t++) {
    // eg loads (plain cached; stream-ordered after k_emb)
    ushort4 egv[4];
    #pragma unroll
    for (int nt = 0; nt < 4; nt++)
      egv[nt] = *(const ushort4*)(eg + ((size_t)t * 32 + b) * GDIM + nt * HDIM + jq);

    f32x4 acc[4];
    #pragma unroll
    for (int nt = 0; nt < 4; nt++) {
      acc[nt][0] = bf2f(egv[nt].x); acc[nt][1] = bf2f(egv[nt].y);
      acc[nt][2] = bf2f(egv[nt].z); acc[nt][3] = bf2f(egv[nt].w);
    }

    if (t > 0) {
      // B-frag: h[b][k = kc*32 + q*8 .. +8] from slot t-1
      // u64 idx in slot: b*128 + kc*8 + q*2 + {0,1}
      const unsigned long long* hp = hbuf + (size_t)(t - 1) * 4096 + b * 128 + q * 2;
      unsigned long long v[32];
      #pragma unroll
      for (int kc = 0; kc < 16; kc++) {       // bulk prefetch: 32 loads in flight
        v[2 * kc]     = allc(hp + kc * 8);
        v[2 * kc + 1] = allc(hp + kc * 8 + 1);
      }
      // PARALLEL respin rounds: reload all 32 (independent) until none SENT.
      for (;;) {
        bool any = false;
        #pragma unroll
        for (int i = 0; i < 32; i++) any |= (v[i] == SENT);
        if (!any) break;
        #pragma unroll
        for (int kc = 0; kc < 16; kc++) {
          v[2 * kc]     = allc(hp + kc * 8);
          v[2 * kc + 1] = allc(hp + kc * 8 + 1);
        }
      }
      #pragma unroll 4
      for (int kc = 0; kc < 16; kc++) {
        BF8 hf; hf.q[0] = v[2 * kc]; hf.q[1] = v[2 * kc + 1];
        #pragma unroll
        for (int nt = 0; nt < 4; nt++) {
          BF8 af; af.v = wlds[((nt * 16 + kc) << 6) + (nl << 2) + q];
          acc[nt] = __builtin_amdgcn_mfma_f32_16x16x32_bf16(af.b, hf.b, acc[nt], 0, 0, 0);
        }
      }
    }

    float4 ov;
    BF4 hb;
    {
      float i0 = sigm(acc[0][0]), f0 = sigm(acc[1][0]), g0v = tanh_(acc[2][0]), o0 = sigm(acc[3][0]);
      float i1 = sigm(acc[0][1]), f1 = sigm(acc[1][1]), g1v = tanh_(acc[2][1]), o1 = sigm(acc[3][1]);
      float i2 = sigm(acc[0][2]), f2 = sigm(acc[1][2]), g2v = tanh_(acc[2][2]), o2 = sigm(acc[3][2]);
      float i3 = sigm(acc[0][3]), f3 = sigm(acc[1][3]), g3v = tanh_(acc[2][3]), o3 = sigm(acc[3][3]);
      ov.x = o0 * tanh_(f0 * c0r[0] + i0 * g0v);   // cell NOT carried: always c0
      ov.y = o1 * tanh_(f1 * c0r[1] + i1 * g1v);
      ov.z = o2 * tanh_(f2 * c0r[2] + i2 * g2v);
      ov.w = o3 * tanh_(f3 * c0r[3] + i3 * g3v);
      hb.u[0] = f2bf(ov.x); hb.u[1] = f2bf(ov.y); hb.u[2] = f2bf(ov.z); hb.u[3] = f2bf(ov.w);
    }
    // h history slot t FIRST (inter-WG critical path): ONE u64 LLC-direct store
    __hip_atomic_store(hbuf + (size_t)t * 4096 + b * 128 + (jq >> 2),
                       hb.q, __ATOMIC_RELAXED, __HIP_MEMORY_SCOPE_AGENT);
    // out[b][t][jq..jq+3] — normal cached store (flushed at kernel end)
    *(float4*)(out + (size_t)b * (SLEN * HDIM) + (size_t)t * HDIM + jq) = ov;
  }
}

// ---------------------------------------------------------------------------
// Workspace (~80.3 MiB):
//   [0,        262144)    const[g][b] f32
//   [262144,  +64 MiB)    eg[s][b][g] bf16 (const baked in)
//   [67371008, +16 MiB)   h history: 512 slots x (32x512 bf16 as u64)
// ---------------------------------------------------------------------------
extern "C" void kernel_launch(void* const* d_in, const int* in_sizes, int n_in,
                              void* d_out, int out_size, void* d_ws, size_t ws_size,
                              hipStream_t stream)
{
  (void)in_sizes; (void)n_in; (void)out_size; (void)ws_size;
  const int*   seq  = (const int*)d_in[0];
  // d_in[1] = enc_out : unused by the reference math
  const float* ench = (const float*)d_in[2];
  const float* encc = (const float*)d_in[3];
  const float* emb  = (const float*)d_in[4];
  const float* Wih  = (const float*)d_in[5];
  const float* Whh  = (const float*)d_in[6];
  const float* bih  = (const float*)d_in[7];
  const float* bhh  = (const float*)d_in[8];
  float* out = (float*)d_out;

  char* ws = (char*)d_ws;
  float*    cgb = (float*)ws;
  uint16_t* eg  = (uint16_t*)(ws + 262144);
  unsigned long long* hbuf = (unsigned long long*)(ws + 67371008);

  hipMemsetAsync(hbuf, 0x7F, (size_t)SLEN * 4096 * 8, stream);   // sentinel fill
  k_const<<<dim3(256),  dim3(256), 0, stream>>>(Whh, ench, bih, bhh, cgb);
  k_emb  <<<dim3(4096), dim3(256), 0, stream>>>(seq, emb, Wih, cgb, eg);
  k_scan <<<dim3(GWG),  dim3(128), 0, stream>>>(Wih, encc, eg, hbuf, out);
}

// Round 6
// 5130.367 us; speedup vs baseline: 1.3883x; 1.3883x over previous
//
#include <hip/hip_runtime.h>
#include <stdint.h>

// Problem constants (DecoderLSTM): VOCAB=50257, E=H=512, B=32, S=512
// ALL float tensors are fp32; sequence is int32. Internal bf16 MFMA; fp32 out.
#define EDIM  512
#define HDIM  512
#define BSZ   32
#define SLEN  512
#define GDIM  2048   // 4*H
#define GWG   32     // number of scan workgroups (h-column split)

typedef __bf16 bf16x8 __attribute__((ext_vector_type(8)));
typedef float  f32x4  __attribute__((ext_vector_type(4)));

__device__ __forceinline__ uint16_t f2bf(float f) {
  union { float f; uint32_t i; } v; v.f = f;
  uint32_t r = v.i + 0x7FFFu + ((v.i >> 16) & 1u);  // RNE
  return (uint16_t)(r >> 16);
}
__device__ __forceinline__ float bf2f(uint32_t u) {
  union { uint32_t i; float f; } v; v.i = u << 16; return v.f;
}
union BF8 { uint16_t u[8]; uint4 v; bf16x8 b; unsigned long long q[2]; };
union BF4 { uint16_t u[4]; unsigned long long q; };
__device__ __forceinline__ uint4 pack8(float4 lo, float4 hi) {
  BF8 r;
  r.u[0] = f2bf(lo.x); r.u[1] = f2bf(lo.y); r.u[2] = f2bf(lo.z); r.u[3] = f2bf(lo.w);
  r.u[4] = f2bf(hi.x); r.u[5] = f2bf(hi.y); r.u[6] = f2bf(hi.z); r.u[7] = f2bf(hi.w);
  return r.v;
}
__device__ __forceinline__ float sigm(float x) { return 1.0f / (1.0f + __expf(-x)); }
__device__ __forceinline__ float tanh_(float x) {
  float ax = fabsf(x);
  float e  = __expf(2.0f * ax);          // overflow-safe: e=inf -> t=1
  float t  = 1.0f - 2.0f / (e + 1.0f);
  return copysignf(t, x);
}
__device__ __forceinline__ unsigned long long allc(const unsigned long long* p) {
  return __hip_atomic_load(p, __ATOMIC_RELAXED, __HIP_MEMORY_SCOPE_AGENT);
}
__device__ __forceinline__ unsigned allc32(const unsigned* p) {
  return __hip_atomic_load(p, __ATOMIC_RELAXED, __HIP_MEMORY_SCOPE_AGENT);
}

// ---------------------------------------------------------------------------
// K1: const[g][b] = sum_k W_hh[g][k]*h0[b][k] + b_ih[g] + b_hh[g] (fp32);
// also zeroes the 32 per-WG flag lines (ws is re-poisoned 0xAA every launch).
// ---------------------------------------------------------------------------
__global__ __launch_bounds__(256) void k_const(
    const float* __restrict__ Whh, const float* __restrict__ h0,
    const float* __restrict__ bih, const float* __restrict__ bhh,
    float* __restrict__ cgb, unsigned* __restrict__ flags)
{
  int idx = blockIdx.x * 256 + threadIdx.x;        // 2048*32 = 65536
  if (idx < 512) flags[idx] = 0u;                  // 32 flags @ 64B stride
  int g = idx >> 5, b = idx & 31;
  const float4* w4 = (const float4*)(Whh + (size_t)g * HDIM);
  const float4* h4 = (const float4*)(h0  + (size_t)b * HDIM);
  float acc = 0.f;
  #pragma unroll 8
  for (int k = 0; k < HDIM / 4; k++) {
    float4 a = w4[k], c = h4[k];
    acc += a.x * c.x + a.y * c.y + a.z * c.z + a.w * c.w;
  }
  acc += bih[g] + bhh[g];
  cgb[idx] = acc;   // layout [g][b]
}

// ---------------------------------------------------------------------------
// K2: eg[s][b][g] (bf16) = sum_e emb[seq[b][s]][e] * W_ih[g][e] + const[g][b]
// Per WG: 64 gate rows (bf16, frag-order, 64KB LDS) x 4 s values.
// MFMA 16x16x32_bf16: A = W_e chunk (M=g), B = gathered emb rows (N=b).
// ---------------------------------------------------------------------------
__global__ __launch_bounds__(256) void k_emb(
    const int* __restrict__ seq, const float* __restrict__ emb,
    const float* __restrict__ Wih, const float* __restrict__ cgb,
    uint16_t* __restrict__ eg)
{
  __shared__ uint4 wlds[4096];   // 64KB bf16, frag-order: [T=n>>4][kc][nl=n&15][q]
  const int tid = threadIdx.x;
  const int gc  = blockIdx.x & 31;   // 32 g-chunks of 64 rows
  const int sc  = blockIdx.x >> 5;   // 128 s-chunks of 4
  const int g0  = gc * 64, s0 = sc * 4;

  for (int i = tid; i < 64 * 64; i += 256) {       // 64 rows x 64 8-elem chunks
    int n = i >> 6, c = i & 63;
    const float* wp = Wih + (size_t)(g0 + n) * 1024 + c * 8;   // W_e = W_ih[:, :512]
    float4 lo = *(const float4*)(wp);
    float4 hi = *(const float4*)(wp + 4);
    wlds[(((n >> 4) * 16 + (c >> 2)) << 6) + ((n & 15) << 2) + (c & 3)] = pack8(lo, hi);
  }
  __syncthreads();

  const int lane = tid & 63, w = tid >> 6;
  const int q = lane >> 4, nl = lane & 15;
  const int Nt  = w & 1;            // b-tile
  const int Mt0 = (w >> 1) * 2;     // g-tile pair {Mt0, Mt0+1}
  const int bcol = Nt * 16 + nl;

  float c0i[4], c1i[4];             // baked const, fixed across s
  #pragma unroll
  for (int r = 0; r < 4; r++) {
    c0i[r] = cgb[(g0 + (Mt0    ) * 16 + q * 4 + r) * 32 + bcol];
    c1i[r] = cgb[(g0 + (Mt0 + 1) * 16 + q * 4 + r) * 32 + bcol];
  }

  for (int si = 0; si < 4; si++) {
    int s = s0 + si;
    int rowi = seq[bcol * SLEN + s];                 // gather index for this lane's b
    const float* brow = emb + (size_t)rowi * EDIM + q * 8;
    f32x4 acc0, acc1;
    #pragma unroll
    for (int r = 0; r < 4; r++) { acc0[r] = c0i[r]; acc1[r] = c1i[r]; }
    #pragma unroll 4
    for (int kc = 0; kc < 16; kc++) {
      float4 blo = *(const float4*)(brow + kc * 32);
      float4 bhi = *(const float4*)(brow + kc * 32 + 4);
      BF8 bf; bf.v = pack8(blo, bhi);
      BF8 a0; a0.v = wlds[(((Mt0    ) * 16 + kc) << 6) + (nl << 2) + q];
      BF8 a1; a1.v = wlds[(((Mt0 + 1) * 16 + kc) << 6) + (nl << 2) + q];
      acc0 = __builtin_amdgcn_mfma_f32_16x16x32_bf16(a0.b, bf.b, acc0, 0, 0, 0);
      acc1 = __builtin_amdgcn_mfma_f32_16x16x32_bf16(a1.b, bf.b, acc1, 0, 0, 0);
    }
    #pragma unroll
    for (int r = 0; r < 4; r++) {
      int m0 = (Mt0    ) * 16 + q * 4 + r;
      int m1 = (Mt0 + 1) * 16 + q * 4 + r;
      eg[((size_t)s * 32 + bcol) * GDIM + g0 + m0] = f2bf(acc0[r]);   // [s][b][g]
      eg[((size_t)s * 32 + bcol) * GDIM + g0 + m1] = f2bf(acc1[r]);
    }
  }
}

// ---------------------------------------------------------------------------
// K3: sequential scan, ping-pong h + per-WG FLAG LINES.
// R6 sync design (fixes R3's hot-line RMW serialization and R4/R5's bulk
// sentinel-poll floods):
//   producer: h u64 sc1 stores + out stores -> __syncthreads (drains vmcnt)
//             -> tid0 STORES flag[wg]=t+1 (own 64B line, no RMW).
//   consumer: wave0 lanes 0..31 each spin on ONE distinct flag line until
//             >= t (32 independent loads per round, 4KB/round device-wide)
//             -> __syncthreads -> ONE-SHOT h burst (no sentinel, no respin).
// Overwrite safety: flag[wg]=t implies wg consumed h(t-2)'s parity slot.
// ---------------------------------------------------------------------------
__global__ __launch_bounds__(128) void k_scan(
    const float* __restrict__ Wih, const float* __restrict__ c0,
    const uint16_t* __restrict__ eg, unsigned long long* __restrict__ hbuf,
    float* __restrict__ out, unsigned* __restrict__ flags)
{
  __shared__ uint4 wlds[4096];   // 64KB
  const int tid = threadIdx.x;
  const int wg  = blockIdx.x;
  const int j0  = wg * 16;

  // Stage W_h slice: row n: gate=n>>4, jj=n&15 -> W_ih row gate*512+j0+jj, cols [512,1024)
  for (int i = tid; i < 64 * 64; i += 128) {
    int n = i >> 6, c = i & 63;
    int grow = (n >> 4) * HDIM + j0 + (n & 15);
    const float* wp = Wih + (size_t)grow * 1024 + 512 + c * 8;
    float4 lo = *(const float4*)(wp);
    float4 hi = *(const float4*)(wp + 4);
    wlds[(((n >> 4) * 16 + (c >> 2)) << 6) + ((n & 15) << 2) + (c & 3)] = pack8(lo, hi);
  }

  const int lane = tid & 63, w = tid >> 6;   // w = batch half (N-tile)
  const int q = lane >> 4, nl = lane & 15;
  const int b  = w * 16 + nl;                // owned batch (C col)
  const int jq = j0 + q * 4;                 // owned j's: jq..jq+3 (C rows)
  float c0r[4];
  #pragma unroll
  for (int r = 0; r < 4; r++) c0r[r] = c0[(size_t)b * HDIM + jq + r];
  __syncthreads();   // LDS W_h ready

  for (int t = 0; t < SLEN; t++) {
    // eg loads (plain cached; stream-ordered after k_emb) — overlap the spin
    ushort4 egv[4];
    #pragma unroll
    for (int nt = 0; nt < 4; nt++)
      egv[nt] = *(const ushort4*)(eg + ((size_t)t * 32 + b) * GDIM + nt * HDIM + jq);

    if (t > 0) {
      if (w == 0) {   // wave 0: lane i polls flag line i (parallel discovery)
        const unsigned* fp = flags + (lane & 31) * 16;
        while (allc32(fp) < (unsigned)t) { }
      }
      __syncthreads();
    }

    f32x4 acc[4];
    #pragma unroll
    for (int nt = 0; nt < 4; nt++) {
      acc[nt][0] = bf2f(egv[nt].x); acc[nt][1] = bf2f(egv[nt].y);
      acc[nt][2] = bf2f(egv[nt].z); acc[nt][3] = bf2f(egv[nt].w);
    }

    if (t > 0) {
      // ONE-SHOT burst: h[b][k = kc*32 + q*8 .. +8] from slot (t-1)&1
      const unsigned long long* hp = hbuf + ((t - 1) & 1) * 4096 + b * 128 + q * 2;
      unsigned long long v[32];
      #pragma unroll
      for (int kc = 0; kc < 16; kc++) {
        v[2 * kc]     = allc(hp + kc * 8);
        v[2 * kc + 1] = allc(hp + kc * 8 + 1);
      }
      #pragma unroll 4
      for (int kc = 0; kc < 16; kc++) {
        BF8 hf; hf.q[0] = v[2 * kc]; hf.q[1] = v[2 * kc + 1];
        #pragma unroll
        for (int nt = 0; nt < 4; nt++) {
          BF8 af; af.v = wlds[((nt * 16 + kc) << 6) + (nl << 2) + q];
          acc[nt] = __builtin_amdgcn_mfma_f32_16x16x32_bf16(af.b, hf.b, acc[nt], 0, 0, 0);
        }
      }
    }

    float4 ov;
    BF4 hb;
    {
      float i0 = sigm(acc[0][0]), f0 = sigm(acc[1][0]), g0v = tanh_(acc[2][0]), o0 = sigm(acc[3][0]);
      float i1 = sigm(acc[0][1]), f1 = sigm(acc[1][1]), g1v = tanh_(acc[2][1]), o1 = sigm(acc[3][1]);
      float i2 = sigm(acc[0][2]), f2 = sigm(acc[1][2]), g2v = tanh_(acc[2][2]), o2 = sigm(acc[3][2]);
      float i3 = sigm(acc[0][3]), f3 = sigm(acc[1][3]), g3v = tanh_(acc[2][3]), o3 = sigm(acc[3][3]);
      ov.x = o0 * tanh_(f0 * c0r[0] + i0 * g0v);   // cell NOT carried: always c0
      ov.y = o1 * tanh_(f1 * c0r[1] + i1 * g1v);
      ov.z = o2 * tanh_(f2 * c0r[2] + i2 * g2v);
      ov.w = o3 * tanh_(f3 * c0r[3] + i3 * g3v);
      hb.u[0] = f2bf(ov.x); hb.u[1] = f2bf(ov.y); hb.u[2] = f2bf(ov.z); hb.u[3] = f2bf(ov.w);
    }
    // h ping-pong slot t&1: ONE u64 sc1 store (inter-WG critical path first)
    __hip_atomic_store(hbuf + (t & 1) * 4096 + b * 128 + (jq >> 2),
                       hb.q, __ATOMIC_RELAXED, __HIP_MEMORY_SCOPE_AGENT);
    // out[b][t][jq..jq+3] — normal cached store (flushed at kernel end)
    *(float4*)(out + (size_t)b * (SLEN * HDIM) + (size_t)t * HDIM + jq) = ov;

    __syncthreads();   // compiler drains vmcnt(0) -> h stores at coherence pt
    if (tid == 0)
      __hip_atomic_store(flags + wg * 16, (unsigned)(t + 1),
                         __ATOMIC_RELAXED, __HIP_MEMORY_SCOPE_AGENT);
  }
}

// ---------------------------------------------------------------------------
// Workspace (~64.3 MiB):
//   [0,       262144)    const[g][b] f32
//   [262144,  264192)    32 flag lines (64B stride)
//   [264192, +64 MiB)    eg[s][b][g] bf16 (const baked in)
//   [67373056, +64 KiB)  h ping-pong: 2 x (32x512 bf16 as u64)
// ---------------------------------------------------------------------------
extern "C" void kernel_launch(void* const* d_in, const int* in_sizes, int n_in,
                              void* d_out, int out_size, void* d_ws, size_t ws_size,
                              hipStream_t stream)
{
  (void)in_sizes; (void)n_in; (void)out_size; (void)ws_size;
  const int*   seq  = (const int*)d_in[0];
  // d_in[1] = enc_out : unused by the reference math
  const float* ench = (const float*)d_in[2];
  const float* encc = (const float*)d_in[3];
  const float* emb  = (const float*)d_in[4];
  const float* Wih  = (const float*)d_in[5];
  const float* Whh  = (const float*)d_in[6];
  const float* bih  = (const float*)d_in[7];
  const float* bhh  = (const float*)d_in[8];
  float* out = (float*)d_out;

  char* ws = (char*)d_ws;
  float*    cgb   = (float*)ws;
  unsigned* flags = (unsigned*)(ws + 262144);
  uint16_t* eg    = (uint16_t*)(ws + 264192);
  unsigned long long* hbuf = (unsigned long long*)(ws + 67373056);

  k_const<<<dim3(256),  dim3(256), 0, stream>>>(Whh, ench, bih, bhh, cgb, flags);
  k_emb  <<<dim3(4096), dim3(256), 0, stream>>>(seq, emb, Wih, cgb, eg);
  k_scan <<<dim3(GWG),  dim3(128), 0, stream>>>(Wih, encc, eg, hbuf, out, flags);
}

// Round 7
// 2971.537 us; speedup vs baseline: 2.3970x; 1.7265x over previous
//
#include <hip/hip_runtime.h>
#include <stdint.h>

// Problem constants (DecoderLSTM): VOCAB=50257, E=H=512, B=32, S=512
// ALL float tensors are fp32; sequence is int32. Internal bf16 MFMA; fp32 out.
#define EDIM  512
#define HDIM  512
#define BSZ   32
#define SLEN  512
#define GDIM  2048   // 4*H
#define GWG   32     // number of scan workgroups (h-column split)

typedef __bf16 bf16x8 __attribute__((ext_vector_type(8)));
typedef float  f32x4  __attribute__((ext_vector_type(4)));

__device__ __forceinline__ uint16_t f2bf(float f) {
  union { float f; uint32_t i; } v; v.f = f;
  uint32_t r = v.i + 0x7FFFu + ((v.i >> 16) & 1u);  // RNE
  return (uint16_t)(r >> 16);
}
__device__ __forceinline__ float bf2f(uint32_t u) {
  union { uint32_t i; float f; } v; v.i = u << 16; return v.f;
}
union BF8 { uint16_t u[8]; uint4 v; bf16x8 b; unsigned long long q[2]; };
union BF4 { uint16_t u[4]; unsigned long long q; };
__device__ __forceinline__ uint4 pack8(float4 lo, float4 hi) {
  BF8 r;
  r.u[0] = f2bf(lo.x); r.u[1] = f2bf(lo.y); r.u[2] = f2bf(lo.z); r.u[3] = f2bf(lo.w);
  r.u[4] = f2bf(hi.x); r.u[5] = f2bf(hi.y); r.u[6] = f2bf(hi.z); r.u[7] = f2bf(hi.w);
  return r.v;
}
__device__ __forceinline__ float sigm(float x) { return 1.0f / (1.0f + __expf(-x)); }
__device__ __forceinline__ float tanh_(float x) {
  float ax = fabsf(x);
  float e  = __expf(2.0f * ax);          // overflow-safe: e=inf -> t=1
  float t  = 1.0f - 2.0f / (e + 1.0f);
  return copysignf(t, x);
}
__device__ __forceinline__ unsigned allc32(const unsigned* p) {
  return __hip_atomic_load(p, __ATOMIC_RELAXED, __HIP_MEMORY_SCOPE_AGENT);
}

// ---------------------------------------------------------------------------
// K1: const[g][b] = sum_k W_hh[g][k]*h0[b][k] + b_ih[g] + b_hh[g] (fp32);
// also zeroes the 32 per-WG flag lines.
// ---------------------------------------------------------------------------
__global__ __launch_bounds__(256) void k_const(
    const float* __restrict__ Whh, const float* __restrict__ h0,
    const float* __restrict__ bih, const float* __restrict__ bhh,
    float* __restrict__ cgb, unsigned* __restrict__ flags)
{
  int idx = blockIdx.x * 256 + threadIdx.x;        // 2048*32 = 65536
  if (idx < 512) flags[idx] = 0u;                  // 32 flags @ 64B stride
  int g = idx >> 5, b = idx & 31;
  const float4* w4 = (const float4*)(Whh + (size_t)g * HDIM);
  const float4* h4 = (const float4*)(h0  + (size_t)b * HDIM);
  float acc = 0.f;
  #pragma unroll 8
  for (int k = 0; k < HDIM / 4; k++) {
    float4 a = w4[k], c = h4[k];
    acc += a.x * c.x + a.y * c.y + a.z * c.z + a.w * c.w;
  }
  acc += bih[g] + bhh[g];
  cgb[idx] = acc;   // layout [g][b]
}

// ---------------------------------------------------------------------------
// K2: eg[s][b][g] (bf16) = sum_e emb[seq[b][s]][e] * W_ih[g][e] + const[g][b]
// Per WG: 64 gate rows (bf16, frag-order, 64KB LDS) x 4 s values.
// MFMA 16x16x32_bf16: A = W_e chunk (M=g), B = gathered emb rows (N=b).
// ---------------------------------------------------------------------------
__global__ __launch_bounds__(256) void k_emb(
    const int* __restrict__ seq, const float* __restrict__ emb,
    const float* __restrict__ Wih, const float* __restrict__ cgb,
    uint16_t* __restrict__ eg)
{
  __shared__ uint4 wlds[4096];   // 64KB bf16, frag-order: [T=n>>4][kc][nl=n&15][q]
  const int tid = threadIdx.x;
  const int gc  = blockIdx.x & 31;   // 32 g-chunks of 64 rows
  const int sc  = blockIdx.x >> 5;   // 128 s-chunks of 4
  const int g0  = gc * 64, s0 = sc * 4;

  for (int i = tid; i < 64 * 64; i += 256) {       // 64 rows x 64 8-elem chunks
    int n = i >> 6, c = i & 63;
    const float* wp = Wih + (size_t)(g0 + n) * 1024 + c * 8;   // W_e = W_ih[:, :512]
    float4 lo = *(const float4*)(wp);
    float4 hi = *(const float4*)(wp + 4);
    wlds[(((n >> 4) * 16 + (c >> 2)) << 6) + ((n & 15) << 2) + (c & 3)] = pack8(lo, hi);
  }
  __syncthreads();

  const int lane = tid & 63, w = tid >> 6;
  const int q = lane >> 4, nl = lane & 15;
  const int Nt  = w & 1;            // b-tile
  const int Mt0 = (w >> 1) * 2;     // g-tile pair {Mt0, Mt0+1}
  const int bcol = Nt * 16 + nl;

  float c0i[4], c1i[4];             // baked const, fixed across s
  #pragma unroll
  for (int r = 0; r < 4; r++) {
    c0i[r] = cgb[(g0 + (Mt0    ) * 16 + q * 4 + r) * 32 + bcol];
    c1i[r] = cgb[(g0 + (Mt0 + 1) * 16 + q * 4 + r) * 32 + bcol];
  }

  for (int si = 0; si < 4; si++) {
    int s = s0 + si;
    int rowi = seq[bcol * SLEN + s];                 // gather index for this lane's b
    const float* brow = emb + (size_t)rowi * EDIM + q * 8;
    f32x4 acc0, acc1;
    #pragma unroll
    for (int r = 0; r < 4; r++) { acc0[r] = c0i[r]; acc1[r] = c1i[r]; }
    #pragma unroll 4
    for (int kc = 0; kc < 16; kc++) {
      float4 blo = *(const float4*)(brow + kc * 32);
      float4 bhi = *(const float4*)(brow + kc * 32 + 4);
      BF8 bf; bf.v = pack8(blo, bhi);
      BF8 a0; a0.v = wlds[(((Mt0    ) * 16 + kc) << 6) + (nl << 2) + q];
      BF8 a1; a1.v = wlds[(((Mt0 + 1) * 16 + kc) << 6) + (nl << 2) + q];
      acc0 = __builtin_amdgcn_mfma_f32_16x16x32_bf16(a0.b, bf.b, acc0, 0, 0, 0);
      acc1 = __builtin_amdgcn_mfma_f32_16x16x32_bf16(a1.b, bf.b, acc1, 0, 0, 0);
    }
    #pragma unroll
    for (int r = 0; r < 4; r++) {
      int m0 = (Mt0    ) * 16 + q * 4 + r;
      int m1 = (Mt0 + 1) * 16 + q * 4 + r;
      eg[((size_t)s * 32 + bcol) * GDIM + g0 + m0] = f2bf(acc0[r]);   // [s][b][g]
      eg[((size_t)s * 32 + bcol) * GDIM + g0 + m1] = f2bf(acc1[r]);
    }
  }
}

// ---------------------------------------------------------------------------
// K3: sequential scan. R7 data-path redesign (R3..R6 showed per-lane uncached
// ATOMIC transactions are the bottleneck — time tracked atomic volume):
//  * h history buffer (512 slots, j-major u64 layout [slot][j/4][b]):
//      producer: ONE sc1 u64 atomic store per lane, COALESCED (16 lanes ->
//      128B contiguous) -> 256 store transactions/step device-wide.
//      consumer: NORMAL CACHED u64 loads (coalesced 128B lines). Safe because
//      slot t-1 addresses were never touched before the flags-wait: no stale
//      L1/L2 copy can exist; L2 miss pulls fresh line from LLC where the
//      producer's drained sc1 stores live.
//  * per-WG flag lines (store-only, no RMW); wave0 lanes poll 32 lines in
//    parallel. Order: h stores -> s_waitcnt vmcnt(0) -> barrier -> flag
//    store -> out store (out kept off the pre-flag drain path).
// ---------------------------------------------------------------------------
__global__ __launch_bounds__(128) void k_scan(
    const float* __restrict__ Wih, const float* __restrict__ c0,
    const uint16_t* __restrict__ eg, unsigned long long* __restrict__ hist,
    float* __restrict__ out, unsigned* __restrict__ flags)
{
  __shared__ uint4 wlds[4096];   // 64KB
  const int tid = threadIdx.x;
  const int wg  = blockIdx.x;
  const int j0  = wg * 16;

  // Stage W_h slice: row n: gate=n>>4, jj=n&15 -> W_ih row gate*512+j0+jj, cols [512,1024)
  for (int i = tid; i < 64 * 64; i += 128) {
    int n = i >> 6, c = i & 63;
    int grow = (n >> 4) * HDIM + j0 + (n & 15);
    const float* wp = Wih + (size_t)grow * 1024 + 512 + c * 8;
    float4 lo = *(const float4*)(wp);
    float4 hi = *(const float4*)(wp + 4);
    wlds[(((n >> 4) * 16 + (c >> 2)) << 6) + ((n & 15) << 2) + (c & 3)] = pack8(lo, hi);
  }

  const int lane = tid & 63, w = tid >> 6;   // w = batch half (N-tile)
  const int q = lane >> 4, nl = lane & 15;
  const int b  = w * 16 + nl;                // owned batch (C col)
  const int jq = j0 + q * 4;                 // owned j's: jq..jq+3 (C rows)
  const int jblk = wg * 4 + q;               // owned j-block (u64 of 4 bf16)
  float c0r[4];
  #pragma unroll
  for (int r = 0; r < 4; r++) c0r[r] = c0[(size_t)b * HDIM + jq + r];
  __syncthreads();   // LDS W_h ready

  for (int t = 0; t < SLEN; t++) {
    // eg loads (plain cached; stream-ordered after k_emb) — overlap the spin
    ushort4 egv[4];
    #pragma unroll
    for (int nt = 0; nt < 4; nt++)
      egv[nt] = *(const ushort4*)(eg + ((size_t)t * 32 + b) * GDIM + nt * HDIM + jq);

    if (t > 0) {
      if (w == 0) {   // wave 0: lane i polls flag line i (parallel discovery)
        const unsigned* fp = flags + (lane & 31) * 16;
        while (allc32(fp) < (unsigned)t) { }
      }
      __syncthreads();
      asm volatile("" ::: "memory");   // no compiler motion of h loads above
    }

    f32x4 acc[4];
    #pragma unroll
    for (int nt = 0; nt < 4; nt++) {
      acc[nt][0] = bf2f(egv[nt].x); acc[nt][1] = bf2f(egv[nt].y);
      acc[nt][2] = bf2f(egv[nt].z); acc[nt][3] = bf2f(egv[nt].w);
    }

    if (t > 0) {
      // NORMAL cached loads, j-major: u64 #(kc*8+q*2+dd)*32 + b, slot t-1.
      // 16 consecutive-b lanes hit one contiguous 128B line.
      const unsigned long long* hp = hist + (size_t)(t - 1) * 4096 + b;
      unsigned long long v[32];
      #pragma unroll
      for (int kc = 0; kc < 16; kc++) {
        v[2 * kc]     = hp[(kc * 8 + q * 2    ) * 32];
        v[2 * kc + 1] = hp[(kc * 8 + q * 2 + 1) * 32];
      }
      #pragma unroll 4
      for (int kc = 0; kc < 16; kc++) {
        BF8 hf; hf.q[0] = v[2 * kc]; hf.q[1] = v[2 * kc + 1];
        #pragma unroll
        for (int nt = 0; nt < 4; nt++) {
          BF8 af; af.v = wlds[((nt * 16 + kc) << 6) + (nl << 2) + q];
          acc[nt] = __builtin_amdgcn_mfma_f32_16x16x32_bf16(af.b, hf.b, acc[nt], 0, 0, 0);
        }
      }
    }

    float4 ov;
    BF4 hb;
    {
      float i0 = sigm(acc[0][0]), f0 = sigm(acc[1][0]), g0v = tanh_(acc[2][0]), o0 = sigm(acc[3][0]);
      float i1 = sigm(acc[0][1]), f1 = sigm(acc[1][1]), g1v = tanh_(acc[2][1]), o1 = sigm(acc[3][1]);
      float i2 = sigm(acc[0][2]), f2 = sigm(acc[1][2]), g2v = tanh_(acc[2][2]), o2 = sigm(acc[3][2]);
      float i3 = sigm(acc[0][3]), f3 = sigm(acc[1][3]), g3v = tanh_(acc[2][3]), o3 = sigm(acc[3][3]);
      ov.x = o0 * tanh_(f0 * c0r[0] + i0 * g0v);   // cell NOT carried: always c0
      ov.y = o1 * tanh_(f1 * c0r[1] + i1 * g1v);
      ov.z = o2 * tanh_(f2 * c0r[2] + i2 * g2v);
      ov.w = o3 * tanh_(f3 * c0r[3] + i3 * g3v);
      hb.u[0] = f2bf(ov.x); hb.u[1] = f2bf(ov.y); hb.u[2] = f2bf(ov.z); hb.u[3] = f2bf(ov.w);
    }
    // h slot t, j-major: ONE coalesced sc1 u64 store per lane
    __hip_atomic_store(hist + (size_t)t * 4096 + (size_t)jblk * 32 + b,
                       hb.q, __ATOMIC_RELAXED, __HIP_MEMORY_SCOPE_AGENT);
    __builtin_amdgcn_s_waitcnt(0x0F70);  // vmcnt(0): h stores at coherence pt
    __syncthreads();                     // all waves drained
    if (tid == 0)
      __hip_atomic_store(flags + wg * 16, (unsigned)(t + 1),
                         __ATOMIC_RELAXED, __HIP_MEMORY_SCOPE_AGENT);
    // out[b][t][jq..jq+3] — cached store, off the pre-flag drain path
    *(float4*)(out + (size_t)b * (SLEN * HDIM) + (size_t)t * HDIM + jq) = ov;
  }
}

// ---------------------------------------------------------------------------
// Workspace (~80.3 MiB):
//   [0,       262144)    const[g][b] f32
//   [262144,  264192)    32 flag lines (64B stride)
//   [264192, +64 MiB)    eg[s][b][g] bf16 (const baked in)
//   [67373056, +16 MiB)  h history: 512 slots x 4096 u64 (j-major [j/4][b])
// ---------------------------------------------------------------------------
extern "C" void kernel_launch(void* const* d_in, const int* in_sizes, int n_in,
                              void* d_out, int out_size, void* d_ws, size_t ws_size,
                              hipStream_t stream)
{
  (void)in_sizes; (void)n_in; (void)out_size; (void)ws_size;
  const int*   seq  = (const int*)d_in[0];
  // d_in[1] = enc_out : unused by the reference math
  const float* ench = (const float*)d_in[2];
  const float* encc = (const float*)d_in[3];
  const float* emb  = (const float*)d_in[4];
  const float* Wih  = (const float*)d_in[5];
  const float* Whh  = (const float*)d_in[6];
  const float* bih  = (const float*)d_in[7];
  const float* bhh  = (const float*)d_in[8];
  float* out = (float*)d_out;

  char* ws = (char*)d_ws;
  float*    cgb   = (float*)ws;
  unsigned* flags = (unsigned*)(ws + 262144);
  uint16_t* eg    = (uint16_t*)(ws + 264192);
  unsigned long long* hist = (unsigned long long*)(ws + 67373056);

  k_const<<<dim3(256),  dim3(256), 0, stream>>>(Whh, ench, bih, bhh, cgb, flags);
  k_emb  <<<dim3(4096), dim3(256), 0, stream>>>(seq, emb, Wih, cgb, eg);
  k_scan <<<dim3(GWG),  dim3(128), 0, stream>>>(Wih, encc, eg, hist, out, flags);
}